// Round 2
// baseline (2763.851 us; speedup 1.0000x reference)
//
#include <hip/hip_runtime.h>

constexpr int NELEM = 100;
constexpr int EMBED = 256;
constexpr int HID   = 512;
constexpr int HEADS = 8;
constexpr int G     = 50;
constexpr int KX    = EMBED + G;  // 306
constexpr int KXP   = 308;        // padded to x4
constexpr int GP    = 52;         // padded to x4
constexpr int TE    = 8;          // edges per block
constexpr int XROW  = 320;        // xs row stride in floats (16B aligned)

// ---- one-time (per launch) weight transpose into workspace ----------------
// W_in [HID][KX] -> W_in_T [KXP][HID]  (rows >= KX zeroed)
// gate_W [HID][G] -> gate_T [GP][HID]  (rows >= G zeroed)
__global__ void transpose_kernel(const float* __restrict__ W_in,
                                 const float* __restrict__ gate_W,
                                 float* __restrict__ W_in_T,
                                 float* __restrict__ gate_T) {
    int idx = blockIdx.x * 256 + threadIdx.x;
    if (idx < KXP * HID) {
        int k = idx / HID, h = idx % HID;
        W_in_T[idx] = (k < KX) ? W_in[h * KX + k] : 0.f;
    }
    if (idx < GP * HID) {
        int g = idx / HID, h = idx % HID;
        gate_T[idx] = (g < G) ? gate_W[h * G + g] : 0.f;
    }
}

// ---- fused main kernel ----------------------------------------------------
__global__ __launch_bounds__(256)
void pair_embed_kernel(const int* __restrict__ anum,
                       const int* __restrict__ edge_index,
                       const int* __restrict__ edge_to_src,
                       const float* __restrict__ dist,
                       const float* __restrict__ emb_table,
                       const float* __restrict__ W_in_T,
                       const float* __restrict__ b_in,
                       const float* __restrict__ gate_T,
                       const float* __restrict__ W_out,
                       const float* __restrict__ b_out,
                       float* __restrict__ out,
                       int E) {
    __shared__ float xs[TE][XROW];      // concat(emb, rbf) per edge
    __shared__ float hv[TE][HID];       // hidden activations
    __shared__ float red[TE][HEADS][4]; // out-proj partial sums
    __shared__ int   rowbase[TE];
    __shared__ float dste[TE];

    const int t  = threadIdx.x;
    const int e0 = blockIdx.x * TE;

    // phase A: per-edge indirection (threads 0..7)
    if (t < TE) {
        int eg = e0 + t;
        int pair = 0; float d = 0.f;
        if (eg < E) {
            int src = edge_to_src[eg];
            int i0  = edge_index[src];
            int i1  = edge_index[E + src];
            pair = anum[i0] + NELEM * anum[i1];
            d = dist[eg];
        }
        rowbase[t] = pair * EMBED;      // float offset into emb_table
        dste[t]    = d;
    }
    __syncthreads();

    // phase B: stage x = [emb(256) | rbf(50) | 0-pad] into LDS
    {
        const int e    = t >> 5;        // 32 threads per edge
        const int lane = t & 31;
        const float4* src = (const float4*)emb_table + (rowbase[e] >> 2);
        float4* dst = (float4*)&xs[e][0];
        dst[lane * 2]     = src[lane * 2];
        dst[lane * 2 + 1] = src[lane * 2 + 1];
        // gaussian smearing
        const float sp    = 12.0f / 49.0f;        // RBF_RADIUS/(G-1)
        const float coeff = -0.5f / (sp * sp);
        float d  = dste[e];
        float dd = d - sp * (float)lane;
        xs[e][EMBED + lane] = __expf(coeff * dd * dd);
        if (lane < GP - 32) {                     // g = 32..51 (zero-pad 50,51)
            int g2 = 32 + lane;
            float v = 0.f;
            if (g2 < G) { float dd2 = d - sp * (float)g2; v = __expf(coeff * dd2 * dd2); }
            xs[e][EMBED + g2] = v;
        }
    }
    __syncthreads();

    // main loop: thread t owns hidden units (2t, 2t+1) for all TE edges
    float acc0[TE], acc1[TE], ga0[TE], ga1[TE];
    #pragma unroll
    for (int e = 0; e < TE; ++e) { acc0[e]=0.f; acc1[e]=0.f; ga0[e]=0.f; ga1[e]=0.f; }

    const float2* WT = (const float2*)W_in_T;   // [KXP][HID/2] float2
    #pragma unroll 2
    for (int kq = 0; kq < KXP / 4; ++kq) {
        const int k = kq * 4;
        float2 w0 = WT[(k+0)*(HID/2) + t];
        float2 w1 = WT[(k+1)*(HID/2) + t];
        float2 w2 = WT[(k+2)*(HID/2) + t];
        float2 w3 = WT[(k+3)*(HID/2) + t];
        #pragma unroll
        for (int e = 0; e < TE; ++e) {
            float4 xv = *(const float4*)&xs[e][k];
            acc0[e] = fmaf(xv.x, w0.x, acc0[e]);
            acc1[e] = fmaf(xv.x, w0.y, acc1[e]);
            acc0[e] = fmaf(xv.y, w1.x, acc0[e]);
            acc1[e] = fmaf(xv.y, w1.y, acc1[e]);
            acc0[e] = fmaf(xv.z, w2.x, acc0[e]);
            acc1[e] = fmaf(xv.z, w2.y, acc1[e]);
            acc0[e] = fmaf(xv.w, w3.x, acc0[e]);
            acc1[e] = fmaf(xv.w, w3.y, acc1[e]);
        }
    }

    const float2* GT = (const float2*)gate_T;   // [GP][HID/2]
    #pragma unroll
    for (int gq = 0; gq < GP / 4; ++gq) {
        const int g = gq * 4;
        float2 w0 = GT[(g+0)*(HID/2) + t];
        float2 w1 = GT[(g+1)*(HID/2) + t];
        float2 w2 = GT[(g+2)*(HID/2) + t];
        float2 w3 = GT[(g+3)*(HID/2) + t];
        #pragma unroll
        for (int e = 0; e < TE; ++e) {
            float4 xv = *(const float4*)&xs[e][EMBED + g];
            ga0[e] = fmaf(xv.x, w0.x, ga0[e]);
            ga1[e] = fmaf(xv.x, w0.y, ga1[e]);
            ga0[e] = fmaf(xv.y, w1.x, ga0[e]);
            ga1[e] = fmaf(xv.y, w1.y, ga1[e]);
            ga0[e] = fmaf(xv.z, w2.x, ga0[e]);
            ga1[e] = fmaf(xv.z, w2.y, ga1[e]);
            ga0[e] = fmaf(xv.w, w3.x, ga0[e]);
            ga1[e] = fmaf(xv.w, w3.y, ga1[e]);
        }
    }

    // silu(pre + b_in) * gate -> hv
    {
        float2 bb = ((const float2*)b_in)[t];
        #pragma unroll
        for (int e = 0; e < TE; ++e) {
            float p0 = acc0[e] + bb.x;
            float p1 = acc1[e] + bb.y;
            float s0 = p0 / (1.f + __expf(-p0));
            float s1 = p1 / (1.f + __expf(-p1));
            hv[e][2*t]   = s0 * ga0[e];
            hv[e][2*t+1] = s1 * ga1[e];
        }
    }
    __syncthreads();

    // out-proj: thread -> (edge, head, quarter of hidden)
    {
        const int e   = t >> 5;
        const int sub = t & 31;
        const int o   = sub >> 2;
        const int p   = sub & 3;
        const float4* wo4 = (const float4*)(W_out + o * HID + p * 128);
        const float* hp  = &hv[e][p * 128];
        float s = 0.f;
        #pragma unroll
        for (int i = 0; i < 32; ++i) {
            float4 w = wo4[i];
            const float* h4 = hp + i * 4;
            s = fmaf(w.x, h4[0], s);
            s = fmaf(w.y, h4[1], s);
            s = fmaf(w.z, h4[2], s);
            s = fmaf(w.w, h4[3], s);
        }
        red[e][o][p] = s;
    }
    __syncthreads();

    if (t < TE * HEADS) {
        const int e = t >> 3;
        const int o = t & 7;
        float s = red[e][o][0] + red[e][o][1] + red[e][o][2] + red[e][o][3]
                + b_out[o];
        int eg = e0 + e;
        if (eg < E) out[o * E + eg] = s;
    }
}

extern "C" void kernel_launch(void* const* d_in, const int* in_sizes, int n_in,
                              void* d_out, int out_size, void* d_ws, size_t ws_size,
                              hipStream_t stream) {
    const int*   anum        = (const int*)d_in[0];
    const int*   edge_index  = (const int*)d_in[1];
    const int*   edge_to_src = (const int*)d_in[2];
    const float* dist        = (const float*)d_in[3];
    const float* emb_table   = (const float*)d_in[4];
    const float* gate_W      = (const float*)d_in[5];
    const float* W_in        = (const float*)d_in[6];
    const float* b_in        = (const float*)d_in[7];
    const float* W_out       = (const float*)d_in[8];
    const float* b_out       = (const float*)d_in[9];
    const int E = in_sizes[3];   // dist has one entry per edge

    float* W_in_T = (float*)d_ws;             // KXP*HID floats
    float* gate_T = W_in_T + KXP * HID;       // GP*HID floats

    transpose_kernel<<<(KXP * HID + 255) / 256, 256, 0, stream>>>(
        W_in, gate_W, W_in_T, gate_T);

    const int nblocks = (E + TE - 1) / TE;
    pair_embed_kernel<<<nblocks, 256, 0, stream>>>(
        anum, edge_index, edge_to_src, dist, emb_table,
        W_in_T, b_in, gate_T, W_out, b_out,
        (float*)d_out, E);
}

// Round 3
// 428.599 us; speedup vs baseline: 6.4486x; 6.4486x over previous
//
#include <hip/hip_runtime.h>

typedef unsigned int uint;
typedef __attribute__((ext_vector_type(8))) short bf16x8;
typedef __attribute__((ext_vector_type(4))) float f32x4;

constexpr int NELEM = 100;
constexpr int EMBED = 256;
constexpr int HID   = 512;
constexpr int KX    = 306;    // EMBED + 50
constexpr int G     = 50;
constexpr int M     = 32;     // edges per block
constexpr int HSTR  = 520;    // hbuf row stride (bf16 elems)

// frag-ready weight buffers in d_ws (bf16):
//  Wb : [10 kstep][32 nt][64 lane][8]  = 163840 elems
//  Gb : [ 2 kstep][32 nt][64 lane][8]  =  32768 elems
//  Ob : [16 kstep][       64 lane][8]  =   8192 elems
constexpr int WB_ELEMS = 10 * 32 * 64 * 8;
constexpr int GB_ELEMS = 2 * 32 * 64 * 8;
constexpr int OB_ELEMS = 16 * 64 * 8;

__device__ __forceinline__ unsigned short f2bf(float x) {
    uint u = __float_as_uint(x);
    u = (u + 0x7fffu + ((u >> 16) & 1u)) >> 16;
    return (unsigned short)u;
}
__device__ __forceinline__ uint pk2(float a, float b) {
    return (uint)f2bf(a) | ((uint)f2bf(b) << 16);
}

__device__ __forceinline__ f32x4 mfma16(bf16x8 a, bf16x8 b, f32x4 c) {
    return __builtin_amdgcn_mfma_f32_16x16x32_bf16(a, b, c, 0, 0, 0);
}

// ---- prep: weights -> fragment-ready bf16 layouts --------------------------
__global__ void prep_kernel(const float* __restrict__ W_in,   // [512][306]
                            const float* __restrict__ gate_W, // [512][50]
                            const float* __restrict__ W_out,  // [8][512]
                            unsigned short* __restrict__ Wb,
                            unsigned short* __restrict__ Gb,
                            unsigned short* __restrict__ Ob) {
    int idx = blockIdx.x * 256 + threadIdx.x;
    if (idx < WB_ELEMS) {
        int j = idx & 7, lane = (idx >> 3) & 63, nt = (idx >> 9) & 31, ks = idx >> 14;
        int h = nt * 16 + (lane & 15);
        int k = ks * 32 + (lane >> 4) * 8 + j;
        Wb[idx] = f2bf((k < KX) ? W_in[h * KX + k] : 0.f);
    } else if (idx < WB_ELEMS + GB_ELEMS) {
        int i2 = idx - WB_ELEMS;
        int j = i2 & 7, lane = (i2 >> 3) & 63, nt = (i2 >> 9) & 31, ks = i2 >> 14;
        int h = nt * 16 + (lane & 15);
        int g = ks * 32 + (lane >> 4) * 8 + j;
        Gb[i2] = f2bf((g < G) ? gate_W[h * G + g] : 0.f);
    } else if (idx < WB_ELEMS + GB_ELEMS + OB_ELEMS) {
        int i2 = idx - WB_ELEMS - GB_ELEMS;
        int j = i2 & 7, lane = (i2 >> 3) & 63, ks = i2 >> 9;
        int n = lane & 15;
        int k = ks * 32 + (lane >> 4) * 8 + j;
        Ob[i2] = f2bf((n < 8) ? W_out[n * HID + k] : 0.f);
    }
}

// ---- fused main kernel -----------------------------------------------------
__global__ __launch_bounds__(256, 2)
void pair_embed_kernel(const int* __restrict__ anum,
                       const int* __restrict__ edge_index,
                       const int* __restrict__ edge_to_src,
                       const float* __restrict__ dist,
                       const float* __restrict__ emb_table,
                       const float* __restrict__ b_in,
                       const float* __restrict__ b_out,
                       const unsigned short* __restrict__ Wb,
                       const unsigned short* __restrict__ Gb,
                       const unsigned short* __restrict__ Ob,
                       float* __restrict__ out,
                       int E) {
    // A-tile, frag-ready: [10 kstep][2 mt][64 lane][8 bf16] = 20 KB
    __shared__ unsigned short afrag[20 * 64 * 8];
    __shared__ unsigned short hbuf[M * HSTR];       // h, plain [m][n] bf16
    __shared__ float red[4][2][64][4];              // out-proj partials
    __shared__ int   rowbase[M];
    __shared__ float dste[M];

    const int t  = threadIdx.x;
    const int e0 = blockIdx.x * M;

    if (t < M) {
        int eg = e0 + t;
        int pair = 0; float d = 0.f;
        if (eg < E) {
            int src = edge_to_src[eg];
            pair = anum[edge_index[src]] + NELEM * anum[edge_index[E + src]];
            d = dist[eg];
        }
        rowbase[t] = pair * EMBED;
        dste[t]    = d;
    }
    __syncthreads();

    // ---- stage A-tile: 1280 chunks of 16B, chunk cix -> afrag[cix*8..] ----
    {
        const float sp    = 12.0f / 49.0f;
        const float coeff = -0.5f / (sp * sp);
        #pragma unroll
        for (int p = 0; p < 5; ++p) {
            int cix  = p * 256 + t;          // 0..1279
            int slot = cix & 63, ks2 = cix >> 6;
            int ks = ks2 >> 1, mt = ks2 & 1;
            int m  = mt * 16 + (slot & 15);
            int sub = slot >> 4;
            uint4 w;
            if (ks < 8) {
                int k0 = ks * 32 + sub * 8;
                const float4* src = (const float4*)(emb_table + rowbase[m] + k0);
                float4 v0 = src[0], v1 = src[1];
                w.x = pk2(v0.x, v0.y); w.y = pk2(v0.z, v0.w);
                w.z = pk2(v1.x, v1.y); w.w = pk2(v1.z, v1.w);
            } else {
                int g0 = (ks - 8) * 32 + sub * 8;
                float d = dste[m];
                float f[8];
                #pragma unroll
                for (int j = 0; j < 8; ++j) {
                    int g = g0 + j;
                    float dd = d - sp * (float)g;
                    f[j] = (g < G) ? __expf(coeff * dd * dd) : 0.f;
                }
                w.x = pk2(f[0], f[1]); w.y = pk2(f[2], f[3]);
                w.z = pk2(f[4], f[5]); w.w = pk2(f[6], f[7]);
            }
            *(uint4*)&afrag[cix * 8] = w;
        }
    }
    __syncthreads();

    const int wave = t >> 6, lane = t & 63;
    const int col = lane & 15, quad = lane >> 4;
    const int ntbase = wave * 8;

    const f32x4 z4 = {0.f, 0.f, 0.f, 0.f};

    // ---- gate GEMM: k-steps 8..9 of A  x  Gb -------------------------------
    f32x4 gacc[8][2];
    #pragma unroll
    for (int nt = 0; nt < 8; ++nt) { gacc[nt][0] = z4; gacc[nt][1] = z4; }
    #pragma unroll
    for (int ks = 0; ks < 2; ++ks) {
        bf16x8 a0 = *(const bf16x8*)&afrag[(((8 + ks) * 2 + 0) * 64 + lane) * 8];
        bf16x8 a1 = *(const bf16x8*)&afrag[(((8 + ks) * 2 + 1) * 64 + lane) * 8];
        #pragma unroll
        for (int nt = 0; nt < 8; ++nt) {
            bf16x8 b = *(const bf16x8*)&Gb[((ks * 32 + ntbase + nt) * 64 + lane) * 8];
            gacc[nt][0] = mfma16(a0, b, gacc[nt][0]);
            gacc[nt][1] = mfma16(a1, b, gacc[nt][1]);
        }
    }

    // ---- main GEMM: k-steps 0..9 of A  x  Wb -------------------------------
    f32x4 acc[8][2];
    #pragma unroll
    for (int nt = 0; nt < 8; ++nt) { acc[nt][0] = z4; acc[nt][1] = z4; }
    #pragma unroll
    for (int ks = 0; ks < 10; ++ks) {
        bf16x8 a0 = *(const bf16x8*)&afrag[((ks * 2 + 0) * 64 + lane) * 8];
        bf16x8 a1 = *(const bf16x8*)&afrag[((ks * 2 + 1) * 64 + lane) * 8];
        #pragma unroll
        for (int nt = 0; nt < 8; ++nt) {
            bf16x8 b = *(const bf16x8*)&Wb[((ks * 32 + ntbase + nt) * 64 + lane) * 8];
            acc[nt][0] = mfma16(a0, b, acc[nt][0]);
            acc[nt][1] = mfma16(a1, b, acc[nt][1]);
        }
    }

    // ---- epilogue: h = silu(acc + b_in) * gacc -> hbuf (bf16) --------------
    #pragma unroll
    for (int nt = 0; nt < 8; ++nt) {
        int hg = wave * 128 + nt * 16 + col;
        float bb = b_in[hg];
        #pragma unroll
        for (int mt = 0; mt < 2; ++mt) {
            #pragma unroll
            for (int r = 0; r < 4; ++r) {
                float pre = acc[nt][mt][r] + bb;
                float s = pre / (1.f + __expf(-pre));
                float h = s * gacc[nt][mt][r];
                int m = mt * 16 + quad * 4 + r;
                hbuf[m * HSTR + hg] = f2bf(h);
            }
        }
    }
    __syncthreads();

    // ---- out-proj: K split across waves (4 k-steps each) -------------------
    f32x4 oacc[2] = {z4, z4};
    #pragma unroll
    for (int kk = 0; kk < 4; ++kk) {
        int ks = wave * 4 + kk;
        bf16x8 b = *(const bf16x8*)&Ob[(ks * 64 + lane) * 8];
        #pragma unroll
        for (int mt = 0; mt < 2; ++mt) {
            bf16x8 a = *(const bf16x8*)&hbuf[(mt * 16 + col) * HSTR + ks * 32 + quad * 8];
            oacc[mt] = mfma16(a, b, oacc[mt]);
        }
    }
    *(float4*)&red[wave][0][lane][0] = *(float4*)&oacc[0];
    *(float4*)&red[wave][1][lane][0] = *(float4*)&oacc[1];
    __syncthreads();

    // ---- final reduce + write ----------------------------------------------
    #pragma unroll
    for (int ii = 0; ii < 2; ++ii) {
        int idx = ii * 256 + t;          // 0..511
        int mt = idx >> 8, l = (idx >> 2) & 63, r = idx & 3;
        float s = red[0][mt][l][r] + red[1][mt][l][r]
                + red[2][mt][l][r] + red[3][mt][l][r];
        int c = l & 15;
        int m = mt * 16 + (l >> 4) * 4 + r;
        int eg = e0 + m;
        if (c < 8 && eg < E) out[c * E + eg] = s + b_out[c];
    }
}

extern "C" void kernel_launch(void* const* d_in, const int* in_sizes, int n_in,
                              void* d_out, int out_size, void* d_ws, size_t ws_size,
                              hipStream_t stream) {
    const int*   anum        = (const int*)d_in[0];
    const int*   edge_index  = (const int*)d_in[1];
    const int*   edge_to_src = (const int*)d_in[2];
    const float* dist        = (const float*)d_in[3];
    const float* emb_table   = (const float*)d_in[4];
    const float* gate_W      = (const float*)d_in[5];
    const float* W_in        = (const float*)d_in[6];
    const float* b_in        = (const float*)d_in[7];
    const float* W_out       = (const float*)d_in[8];
    const float* b_out       = (const float*)d_in[9];
    const int E = in_sizes[3];

    unsigned short* Wb = (unsigned short*)d_ws;
    unsigned short* Gb = Wb + WB_ELEMS;
    unsigned short* Ob = Gb + GB_ELEMS;

    int total = WB_ELEMS + GB_ELEMS + OB_ELEMS;
    prep_kernel<<<(total + 255) / 256, 256, 0, stream>>>(W_in, gate_W, W_out, Wb, Gb, Ob);

    const int nblocks = (E + M - 1) / M;
    pair_embed_kernel<<<nblocks, 256, 0, stream>>>(
        anum, edge_index, edge_to_src, dist, emb_table,
        b_in, b_out, Wb, Gb, Ob, (float*)d_out, E);
}